// Round 2
// 3507.446 us; speedup vs baseline: 1.0683x; 1.0683x over previous
//
#include <hip/hip_runtime.h>

// GPT forward (B=8,S=512,D=768,H=12,L=12,FF=3072) on gfx950.
// R2: + global_load_lds(16B) async staging; split-K for Wo(x2)/Wp2(x4) with
//     fused reduce+bias+residual+LayerNorm epilogue kernel.
// R3: fused flash-style attention (QK^T+mask+softmax+PV in one kernel,
//     causal chunk skipping, swizzled P in LDS). Deletes scores GEMM,
//     softmax_k, PV GEMM (-36 dispatches, -~200MB/layer cache traffic).
// R3b: resubmit after container-level infra failure (kernel re-audited:
//     uniform barriers, dbuf parity, swizzle bijectivity, bounds all OK).

typedef unsigned short u16;
typedef unsigned int u32;
typedef __bf16 bf16x8 __attribute__((ext_vector_type(8)));
typedef float f32x4 __attribute__((ext_vector_type(4)));

__device__ __forceinline__ float bf2f(u16 u) {
    union { unsigned int i; float f; } c; c.i = ((unsigned int)u) << 16; return c.f;
}
__device__ __forceinline__ u16 f2bf(float f) {
    union { float f; unsigned int i; } c; c.f = f;
    unsigned int b = c.i;
    return (u16)((b + 0x7fffu + ((b >> 16) & 1u)) >> 16);
}
__device__ __forceinline__ float gelu_f(float x) {
    float y = 0.7978845608028654f * (x + 0.044715f * x * x * x);
    float t = __expf(2.0f * y);
    float th = 1.0f - 2.0f / (t + 1.0f);  // tanh(y)
    return 0.5f * x * (1.0f + th);
}
// Async global->LDS 16B per lane. LDS dest is wave-uniform base + lane*16.
__device__ __forceinline__ void async_cp16(const u16* g, u16* l) {
    __builtin_amdgcn_global_load_lds(
        (const __attribute__((address_space(1))) u32*)g,
        (__attribute__((address_space(3))) u32*)l, 16, 0, 0);
}

// ---------------------------------------------------------------------------
// GEMM: C[M][N] = A[M][K] @ Bt[N][K]^T (+epilogue). A,Bt bf16. 256 threads.
// Batched over blockIdx.z (z = zb*Hh + zh). LDS fragment-permuted layout:
// (row,k) -> vec8 slot ((row/16)*2 + (k/32))*64 + ((k%32)/8)*16 + (row%16).
// EPI: 0 = raw fp32 partial store (split-K), 1 = bias+bf16,
//      3 = bias+gelu bf16, 4 = bias+residual fp32.
// ---------------------------------------------------------------------------
template<int BM, int BN, int WR, int WC, int EPI>
__global__ __launch_bounds__(256) void gemm_k(
    const u16* __restrict__ A, int lda, long long aSB, long long aSH,
    const u16* __restrict__ Bt, int ldb, long long bSB, long long bSH,
    void* __restrict__ Cv, int ldc, long long cSB, long long cSH,
    const float* __restrict__ bias, const float* __restrict__ res,
    const int* __restrict__ amask,
    int K, int Hh)
{
    constexpr int BK = 64;
    constexpr int WM = BM / WR, WN = BN / WC;
    constexpr int FM = WM / 16, FN = WN / 16;
    __shared__ __align__(16) u16 As[BM * BK];
    __shared__ __align__(16) u16 Bs[BN * BK];
    const int t = threadIdx.x;
    const int lane = t & 63;
    const int w = t >> 6;
    const int wr = w / WC, wc = w % WC;
    const int zb = blockIdx.z / Hh, zh = blockIdx.z % Hh;
    const u16* Ab = A + zb * aSB + zh * aSH + (size_t)blockIdx.x * BM * lda;
    const u16* Bb = Bt + zb * bSB + zh * bSH + (size_t)blockIdx.y * BN * ldb;

    f32x4 acc[FM][FN];
#pragma unroll
    for (int i = 0; i < FM; ++i)
#pragma unroll
        for (int j = 0; j < FN; ++j)
            acc[i][j] = (f32x4){0.f, 0.f, 0.f, 0.f};

    for (int k0 = 0; k0 < K; k0 += BK) {
        __syncthreads();
#pragma unroll
        for (int p = 0; p < (BM * BK) / 2048; ++p) {
            int idx8 = p * 256 + t;
            int grp = idx8 >> 6, l6 = idx8 & 63;
            int row = (grp >> 1) * 16 + (l6 & 15);
            int k = (grp & 1) * 32 + (l6 >> 4) * 8;
            int base8 = p * 256 + (t & ~63);  // wave-uniform LDS base
            async_cp16(Ab + (size_t)row * lda + k0 + k, &As[(size_t)base8 * 8]);
        }
#pragma unroll
        for (int p = 0; p < (BN * BK) / 2048; ++p) {
            int idx8 = p * 256 + t;
            int grp = idx8 >> 6, l6 = idx8 & 63;
            int row = (grp >> 1) * 16 + (l6 & 15);
            int k = (grp & 1) * 32 + (l6 >> 4) * 8;
            int base8 = p * 256 + (t & ~63);
            async_cp16(Bb + (size_t)row * ldb + k0 + k, &Bs[(size_t)base8 * 8]);
        }
        __syncthreads();
#pragma unroll
        for (int ks = 0; ks < 2; ++ks) {
            bf16x8 aF[FM], bF[FN];
#pragma unroll
            for (int i = 0; i < FM; ++i) {
                int gA = (wr * WM) / 16 + i;
                aF[i] = *(const bf16x8*)(&As[((gA * 2 + ks) * 64 + lane) * 8]);
            }
#pragma unroll
            for (int j = 0; j < FN; ++j) {
                int gB = (wc * WN) / 16 + j;
                bF[j] = *(const bf16x8*)(&Bs[((gB * 2 + ks) * 64 + lane) * 8]);
            }
#pragma unroll
            for (int i = 0; i < FM; ++i)
#pragma unroll
                for (int j = 0; j < FN; ++j)
                    acc[i][j] = __builtin_amdgcn_mfma_f32_16x16x32_bf16(
                        aF[i], bF[j], acc[i][j], 0, 0, 0);
        }
    }

    // C/D layout: col = lane&15, row = (lane>>4)*4 + reg.
    const int q = lane >> 4, cn = lane & 15;
#pragma unroll
    for (int i = 0; i < FM; ++i) {
#pragma unroll
        for (int j = 0; j < FN; ++j) {
            int mBase = blockIdx.x * BM + wr * WM + i * 16 + q * 4;
            int n0 = blockIdx.y * BN + wc * WN + j * 16 + cn;
#pragma unroll
            for (int r = 0; r < 4; ++r) {
                int m = mBase + r;
                float v = acc[i][j][r];
                if constexpr (EPI == 0) {  // fp32 partial (split-K)
                    float* Cp = (float*)Cv + zb * cSB + zh * cSH;
                    Cp[(size_t)m * ldc + n0] = v;
                } else if constexpr (EPI == 1) {
                    if (bias) v += bias[n0];
                    u16* Cp = (u16*)Cv + zb * cSB + zh * cSH;
                    Cp[(size_t)m * ldc + n0] = f2bf(v);
                } else if constexpr (EPI == 3) {
                    v += bias[n0];
                    v = gelu_f(v);
                    u16* Cp = (u16*)Cv + zb * cSB + zh * cSH;
                    Cp[(size_t)m * ldc + n0] = f2bf(v);
                } else {  // EPI == 4
                    v += bias[n0] + res[(size_t)m * ldc + n0];
                    float* Cp = (float*)Cv + zb * cSB + zh * cSH;
                    Cp[(size_t)m * ldc + n0] = v;
                }
            }
        }
    }
}

// Weight transpose+convert: src fp32 [K][N] -> dst bf16 [N][K], batch z.
__global__ __launch_bounds__(256) void transpose_w_k(
    const float* __restrict__ src, u16* __restrict__ dst, int K, int N)
{
    __shared__ float tile[32][33];
    const int n0 = blockIdx.x * 32, k0 = blockIdx.y * 32;
    const size_t zoff = (size_t)blockIdx.z * K * N;
    src += zoff;
    dst += zoff;
    const int tx = threadIdx.x & 31, ty = threadIdx.x >> 5;
#pragma unroll
    for (int i = 0; i < 4; ++i) {
        int k = k0 + ty + i * 8;
        tile[ty + i * 8][tx] = src[(size_t)k * N + n0 + tx];
    }
    __syncthreads();
#pragma unroll
    for (int i = 0; i < 4; ++i) {
        int n = n0 + ty + i * 8;
        dst[(size_t)n * K + k0 + tx] = f2bf(tile[tx][ty + i * 8]);
    }
}

// V transpose: Vt[z][d][j] = qkv[b*512+j][1536 + h*64 + d], bf16.
__global__ __launch_bounds__(256) void vtrans_k(
    const u16* __restrict__ qkv, u16* __restrict__ vt)
{
    __shared__ u16 tile[32][66];
    const int z = blockIdx.y;
    const int b = z / 12, h = z % 12;
    const int jc = blockIdx.x * 32;
    const int d = threadIdx.x & 63, jj = threadIdx.x >> 6;
    const u16* src = qkv + (size_t)b * 512 * 2304 + 1536 + (size_t)h * 64;
#pragma unroll
    for (int i = 0; i < 8; ++i) {
        int j = jc + jj + i * 4;
        tile[jj + i * 4][d] = src[(size_t)j * 2304 + d];
    }
    __syncthreads();
    const int jx = threadIdx.x & 31, dd0 = threadIdx.x >> 5;
    u16* dstz = vt + (size_t)z * 64 * 512;
#pragma unroll
    for (int i = 0; i < 8; ++i) {
        int dd = dd0 + i * 8;
        dstz[(size_t)dd * 512 + jc + jx] = tile[jx][dd];
    }
}

// ---------------------------------------------------------------------------
// Fused attention: per block = 32 q-rows of one (b,h). S=512, dh=64.
// Phase A: S = Q K^T over nch causal chunks of 64 (full row in regs).
// Softmax in regs (shfl within 16-lane group + LDS cross-wave reduce).
// P (unnormalized bf16) -> swizzled LDS. Phase B: attn = P @ V^T chunks.
// 1/sum applied at epilogue (same per-lane row map in both phases).
// ---------------------------------------------------------------------------
__global__ __launch_bounds__(256) void fattn_k(
    const u16* __restrict__ qkv, const u16* __restrict__ vt,
    u16* __restrict__ out, const int* __restrict__ amask)
{
    __shared__ __align__(16) u16 Qs[32 * 64];        // 4KB, frag layout
    __shared__ __align__(16) u16 KVs[2][64 * 64];    // 16KB dbuf, frag layout
    __shared__ __align__(16) u16 Ps[32 * 512];       // 32KB, swizzled row-major
    __shared__ float red[4][32];

    const int t = threadIdx.x;
    const int lane = t & 63;
    const int w = t >> 6;              // wave id: col tile (phase A) / d tile (B)
    const int q4 = lane >> 4, cn = lane & 15;
    const int z = blockIdx.x;          // 96 = b*12+h
    const int b = z / 12, h = z % 12;
    const int x = 15 - (int)blockIdx.y;  // heavy (large-nch) tiles dispatch first
    const int q0 = x * 32;
    const int nch = (q0 + 32 + 63) >> 6;  // causal: chunks of 64 cols, 1..8

    const u16* Qg = qkv + (size_t)(b * 512 + q0) * 2304 + h * 64;
    const u16* Kg = qkv + (size_t)(b * 512) * 2304 + 768 + h * 64;
    const u16* Vg = vt + (size_t)z * 64 * 512;

    // ---- stage Q (32x64 -> frag layout, one 16B op/thread) + K chunk 0 ----
    {
        int grp = t >> 6, l6 = t & 63;
        int row = (grp >> 1) * 16 + (l6 & 15);
        int k = (grp & 1) * 32 + (l6 >> 4) * 8;
        int base8 = t & ~63;
        async_cp16(Qg + (size_t)row * 2304 + k, &Qs[base8 * 8]);
    }
    auto stageK = [&](int c, int buf) {
#pragma unroll
        for (int p = 0; p < 2; ++p) {
            int idx8 = p * 256 + t;
            int grp = idx8 >> 6, l6 = idx8 & 63;
            int row = (grp >> 1) * 16 + (l6 & 15);   // j within chunk
            int k = (grp & 1) * 32 + (l6 >> 4) * 8;  // d
            int base8 = p * 256 + (t & ~63);
            async_cp16(Kg + (size_t)(c * 64 + row) * 2304 + k,
                       &KVs[buf][base8 * 8]);
        }
    };
    auto stageV = [&](int c, int buf) {
#pragma unroll
        for (int p = 0; p < 2; ++p) {
            int idx8 = p * 256 + t;
            int grp = idx8 >> 6, l6 = idx8 & 63;
            int row = (grp >> 1) * 16 + (l6 & 15);   // d
            int k = (grp & 1) * 32 + (l6 >> 4) * 8;  // j within chunk
            int base8 = p * 256 + (t & ~63);
            async_cp16(Vg + (size_t)row * 512 + c * 64 + k,
                       &KVs[buf][base8 * 8]);
        }
    };
    stageK(0, 0);
    __syncthreads();

    bf16x8 qF[2][2];
#pragma unroll
    for (int i = 0; i < 2; ++i)
#pragma unroll
        for (int ks = 0; ks < 2; ++ks)
            qF[i][ks] = *(const bf16x8*)(&Qs[((i * 2 + ks) * 64 + lane) * 8]);

    f32x4 acc[2][8];
#pragma unroll
    for (int i = 0; i < 2; ++i)
#pragma unroll
        for (int c = 0; c < 8; ++c)
            acc[i][c] = (f32x4){0.f, 0.f, 0.f, 0.f};

    // ---- Phase A: S chunks. wave w computes cols w*16+cn of each chunk ----
#pragma unroll
    for (int c = 0; c < 8; ++c) {
        if (c < nch) {  // block-uniform
            if (c + 1 < nch) stageK(c + 1, (c + 1) & 1);
            else stageV(0, nch & 1);  // prefetch first V chunk
            const u16* Kb = KVs[c & 1];
#pragma unroll
            for (int ks = 0; ks < 2; ++ks) {
                bf16x8 bF = *(const bf16x8*)(&Kb[((w * 2 + ks) * 64 + lane) * 8]);
#pragma unroll
                for (int i = 0; i < 2; ++i)
                    acc[i][c] = __builtin_amdgcn_mfma_f32_16x16x32_bf16(
                        qF[i][ks], bF, acc[i][c], 0, 0, 0);
            }
            __syncthreads();
        }
    }

    // ---- mask + scale; running max ----
    float mx[2][4];
#pragma unroll
    for (int i = 0; i < 2; ++i)
#pragma unroll
        for (int r = 0; r < 4; ++r) mx[i][r] = -1e30f;
#pragma unroll
    for (int c = 0; c < 8; ++c) {
        if (c < nch) {
            int j = c * 64 + w * 16 + cn;
            float am = (1.0f - (float)amask[b * 512 + j]) * -10000.0f;
#pragma unroll
            for (int i = 0; i < 2; ++i)
#pragma unroll
                for (int r = 0; r < 4; ++r) {
                    int q = q0 + i * 16 + q4 * 4 + r;
                    float s = (j <= q) ? (acc[i][c][r] * 0.125f + am)
                                       : (-10000.0f + am);
                    acc[i][c][r] = s;
                    mx[i][r] = fmaxf(mx[i][r], s);
                }
        }
    }
#pragma unroll
    for (int i = 0; i < 2; ++i)
#pragma unroll
        for (int r = 0; r < 4; ++r) {
            float m = mx[i][r];
            m = fmaxf(m, __shfl_xor(m, 1));
            m = fmaxf(m, __shfl_xor(m, 2));
            m = fmaxf(m, __shfl_xor(m, 4));
            m = fmaxf(m, __shfl_xor(m, 8));
            mx[i][r] = m;
        }
    if (cn == 0) {
#pragma unroll
        for (int i = 0; i < 2; ++i)
#pragma unroll
            for (int r = 0; r < 4; ++r)
                red[w][i * 16 + q4 * 4 + r] = mx[i][r];
    }
    __syncthreads();
#pragma unroll
    for (int i = 0; i < 2; ++i)
#pragma unroll
        for (int r = 0; r < 4; ++r) {
            int q = i * 16 + q4 * 4 + r;
            mx[i][r] = fmaxf(fmaxf(red[0][q], red[1][q]),
                             fmaxf(red[2][q], red[3][q]));
        }
    __syncthreads();  // before red reuse for sums

    // ---- exp, write P (unnormalized bf16, swizzled), row sums ----
    float sm[2][4];
#pragma unroll
    for (int i = 0; i < 2; ++i)
#pragma unroll
        for (int r = 0; r < 4; ++r) sm[i][r] = 0.f;
#pragma unroll
    for (int c = 0; c < 8; ++c) {
        if (c < nch) {
            int j = c * 64 + w * 16 + cn;
#pragma unroll
            for (int i = 0; i < 2; ++i)
#pragma unroll
                for (int r = 0; r < 4; ++r) {
                    float p = __expf(acc[i][c][r] - mx[i][r]);
                    sm[i][r] += p;
                    int row = i * 16 + q4 * 4 + r;
                    int sw = (row & 7) ^ ((row >> 3) & 1);
                    Ps[row * 512 + (j ^ (sw << 3))] = f2bf(p);
                }
        }
    }
#pragma unroll
    for (int i = 0; i < 2; ++i)
#pragma unroll
        for (int r = 0; r < 4; ++r) {
            float s = sm[i][r];
            s += __shfl_xor(s, 1);
            s += __shfl_xor(s, 2);
            s += __shfl_xor(s, 4);
            s += __shfl_xor(s, 8);
            sm[i][r] = s;
        }
    if (cn == 0) {
#pragma unroll
        for (int i = 0; i < 2; ++i)
#pragma unroll
            for (int r = 0; r < 4; ++r)
                red[w][i * 16 + q4 * 4 + r] = sm[i][r];
    }
    __syncthreads();
    float inv[2][4];
#pragma unroll
    for (int i = 0; i < 2; ++i)
#pragma unroll
        for (int r = 0; r < 4; ++r) {
            int q = i * 16 + q4 * 4 + r;
            inv[i][r] = 1.0f / (red[0][q] + red[1][q] + red[2][q] + red[3][q]);
        }

    // ---- Phase B: attn = P @ V. wave w computes d cols w*16+cn ----
    f32x4 acc2[2];
    acc2[0] = (f32x4){0.f, 0.f, 0.f, 0.f};
    acc2[1] = (f32x4){0.f, 0.f, 0.f, 0.f};
#pragma unroll
    for (int c = 0; c < 8; ++c) {
        if (c < nch) {
            if (c + 1 < nch) stageV(c + 1, (nch + c + 1) & 1);
            const u16* Vb = KVs[(nch + c) & 1];
#pragma unroll
            for (int ks = 0; ks < 2; ++ks) {
                bf16x8 vF = *(const bf16x8*)(&Vb[((w * 2 + ks) * 64 + lane) * 8]);
                int jb = c * 64 + ks * 32 + q4 * 8;
#pragma unroll
                for (int i = 0; i < 2; ++i) {
                    int prow = i * 16 + cn;
                    int sw = (prow & 7) ^ ((prow >> 3) & 1);
                    bf16x8 pF = *(const bf16x8*)(
                        &Ps[prow * 512 + (jb ^ (sw << 3))]);
                    acc2[i] = __builtin_amdgcn_mfma_f32_16x16x32_bf16(
                        pF, vF, acc2[i], 0, 0, 0);
                }
            }
            __syncthreads();
        }
    }

    // ---- epilogue: scale by 1/sum, write bf16 [4096][768] ----
#pragma unroll
    for (int i = 0; i < 2; ++i)
#pragma unroll
        for (int r = 0; r < 4; ++r) {
            int q = q0 + i * 16 + q4 * 4 + r;
            out[(size_t)(b * 512 + q) * 768 + h * 64 + w * 16 + cn] =
                f2bf(acc2[i][r] * inv[i][r]);
        }
}

// Fused split-K reduce + bias + residual + LayerNorm. One block per row.
// x = sum_p parts[p] + bias + res ; out = LN(x)*g + b (fp32 + bf16 copies).
template<int NP>
__global__ __launch_bounds__(256) void reduce_ln_k(
    const float* __restrict__ parts, const float* __restrict__ bias,
    const float* __restrict__ res, const float* __restrict__ g,
    const float* __restrict__ b, float* __restrict__ out, u16* __restrict__ outb)
{
    __shared__ float red[4];
    const int r = blockIdx.x, t = threadIdx.x;
    const size_t base = (size_t)r * 768;
    float v[3];
#pragma unroll
    for (int i = 0; i < 3; ++i) {
        const int d = t + i * 256;
        float x = res[base + d] + bias[d];
#pragma unroll
        for (int p = 0; p < NP; ++p)
            x += parts[(size_t)p * 4096 * 768 + base + d];
        v[i] = x;
    }
    float s = v[0] + v[1] + v[2];
    for (int o = 1; o < 64; o <<= 1) s += __shfl_xor(s, o);
    if ((t & 63) == 0) red[t >> 6] = s;
    __syncthreads();
    const float mean = (red[0] + red[1] + red[2] + red[3]) * (1.0f / 768.0f);
    __syncthreads();
    float d0 = v[0] - mean, d1 = v[1] - mean, d2 = v[2] - mean;
    float s2 = d0 * d0 + d1 * d1 + d2 * d2;
    for (int o = 1; o < 64; o <<= 1) s2 += __shfl_xor(s2, o);
    if ((t & 63) == 0) red[t >> 6] = s2;
    __syncthreads();
    const float var = (red[0] + red[1] + red[2] + red[3]) * (1.0f / 768.0f);
    const float rs = rsqrtf(var + 1e-5f);
    float y0 = d0 * rs * g[t] + b[t];
    float y1 = d1 * rs * g[t + 256] + b[t + 256];
    float y2 = d2 * rs * g[t + 512] + b[t + 512];
    out[base + t] = y0; out[base + t + 256] = y1; out[base + t + 512] = y2;
    outb[base + t] = f2bf(y0);
    outb[base + t + 256] = f2bf(y1);
    outb[base + t + 512] = f2bf(y2);
}

// Embedding: h[r][d] = tok[ids[r]][d] + pos[r%512][d]; also bf16 copy.
__global__ __launch_bounds__(256) void embed_k(
    const int* __restrict__ ids, const float* __restrict__ tok,
    const float* __restrict__ pos, float* __restrict__ h, u16* __restrict__ hb)
{
    const int e = blockIdx.x * 256 + threadIdx.x;
    const int r = e / 768, d = e - r * 768;
    const int srow = r & 511;
    const int id = ids[r];
    const float v = tok[(size_t)id * 768 + d] + pos[(size_t)srow * 768 + d];
    h[e] = v;
    hb[e] = f2bf(v);
}

extern "C" void kernel_launch(void* const* d_in, const int* in_sizes, int n_in,
                              void* d_out, int out_size, void* d_ws, size_t ws_size,
                              hipStream_t stream)
{
    (void)in_sizes; (void)n_in; (void)out_size; (void)ws_size;
    const int*   ids  = (const int*)d_in[0];
    const int*   mask = (const int*)d_in[1];
    const float* tok  = (const float*)d_in[2];
    const float* pos  = (const float*)d_in[3];
    const float* Wqkv = (const float*)d_in[4];
    const float* bqkv = (const float*)d_in[5];
    const float* Wo   = (const float*)d_in[6];
    const float* bo   = (const float*)d_in[7];
    const float* g1   = (const float*)d_in[8];
    const float* b1   = (const float*)d_in[9];
    const float* Wfc  = (const float*)d_in[10];
    const float* bfc  = (const float*)d_in[11];
    const float* Wp2  = (const float*)d_in[12];
    const float* bp2  = (const float*)d_in[13];
    const float* g2   = (const float*)d_in[14];
    const float* b2   = (const float*)d_in[15];

    char* ws = (char*)d_ws;
    size_t off = 0;
    auto alloc = [&](size_t elems, size_t esz) {
        void* p = ws + off;
        off += (elems * esz + 255) & ~(size_t)255;
        return p;
    };
    u16*   WqkvT  = (u16*)alloc(12ull * 2304 * 768, 2);
    u16*   WoT    = (u16*)alloc(12ull * 768 * 768, 2);
    u16*   WfcT   = (u16*)alloc(12ull * 3072 * 768, 2);
    u16*   Wp2T   = (u16*)alloc(12ull * 768 * 3072, 2);
    float* h      = (float*)alloc(4096ull * 768, 4);
    u16*   hb     = (u16*)alloc(4096ull * 768, 2);
    u16*   qkvb   = (u16*)alloc(4096ull * 2304, 2);
    u16*   scores = (u16*)alloc(96ull * 512 * 512, 2);   // now only P2 partials
    u16*   Vt     = (u16*)alloc(96ull * 64 * 512, 2);
    u16*   attnb  = (u16*)alloc(4096ull * 768, 2);
    float* nbuf   = (float*)alloc(4096ull * 768, 4);
    u16*   nb     = (u16*)alloc(4096ull * 768, 2);
    u16*   fcb    = (u16*)alloc(4096ull * 3072, 2);      // aliased as P1 (2x fp32)
    float* P1 = (float*)fcb;     // 2*4096*768*4 B == 4096*3072*2 B
    float* P2 = (float*)scores;  // 4*4096*768*4 B == 96*512*512*2 B

    transpose_w_k<<<dim3(72, 24, 12), 256, 0, stream>>>(Wqkv, WqkvT, 768, 2304);
    transpose_w_k<<<dim3(24, 24, 12), 256, 0, stream>>>(Wo, WoT, 768, 768);
    transpose_w_k<<<dim3(96, 24, 12), 256, 0, stream>>>(Wfc, WfcT, 768, 3072);
    transpose_w_k<<<dim3(24, 96, 12), 256, 0, stream>>>(Wp2, Wp2T, 3072, 768);
    embed_k<<<12288, 256, 0, stream>>>(ids, tok, pos, h, hb);

    for (int l = 0; l < 12; ++l) {
        // qkv = h @ Wqkv + bqkv -> bf16 [4096][2304]
        gemm_k<128, 128, 2, 2, 1><<<dim3(32, 18, 1), 256, 0, stream>>>(
            hb, 768, 0, 0, WqkvT + (size_t)l * 2304 * 768, 768, 0, 0,
            qkvb, 2304, 0, 0, bqkv + l * 2304, nullptr, nullptr, 768, 1);
        // Vt[z][d][j] for PV B-operand
        vtrans_k<<<dim3(16, 96), 256, 0, stream>>>(qkvb, Vt);
        // fused attention: QK^T + mask + softmax + PV -> attnb [4096][768]
        fattn_k<<<dim3(96, 16), 256, 0, stream>>>(qkvb, Vt, attnb, mask);
        // Wo, split-K=2 -> P1 partials (z = split)
        gemm_k<128, 128, 2, 2, 0><<<dim3(32, 6, 2), 256, 0, stream>>>(
            attnb, 768, 0, 384, WoT + (size_t)l * 768 * 768, 768, 0, 384,
            P1, 768, 0, 4096LL * 768, nullptr, nullptr, nullptr, 384, 2);
        // n = LN(h + attn@Wo + bo) -> nbuf fp32 + nb bf16
        reduce_ln_k<2><<<4096, 256, 0, stream>>>(
            P1, bo + l * 768, h, g1 + l * 768, b1 + l * 768, nbuf, nb);
        // fc = gelu(n @ Wfc + bfc) -> bf16 [4096][3072]  (overwrites P1)
        gemm_k<128, 128, 2, 2, 3><<<dim3(32, 24, 1), 256, 0, stream>>>(
            nb, 768, 0, 0, WfcT + (size_t)l * 3072 * 768, 768, 0, 0,
            fcb, 3072, 0, 0, bfc + l * 3072, nullptr, nullptr, 768, 1);
        // Wp2, split-K=4 -> P2 partials (overwrites scores region)
        gemm_k<128, 128, 2, 2, 0><<<dim3(32, 6, 4), 256, 0, stream>>>(
            fcb, 3072, 0, 768, Wp2T + (size_t)l * 768 * 3072, 3072, 0, 768,
            P2, 768, 0, 4096LL * 768, nullptr, nullptr, nullptr, 768, 4);
        // h' = LN(n + fc@Wp2 + bp2) -> h/d_out fp32 + hb bf16
        float* dsth = (l == 11) ? (float*)d_out : h;
        reduce_ln_k<4><<<4096, 256, 0, stream>>>(
            P2, bp2 + l * 768, nbuf, g2 + l * 768, b2 + l * 768, dsth, hb);
    }
}

// Round 3
// 2840.207 us; speedup vs baseline: 1.3192x; 1.2349x over previous
//
#include <hip/hip_runtime.h>

// GPT forward (B=8,S=512,D=768,H=12,L=12,FF=3072) on gfx950.
// R3: fused flash-style attention (QK^T+mask+softmax+PV one kernel).
// R4: all GEMMs -> 256x256 8-wave 8-phase schedule (T3+T4+T5): raw s_barrier
//     (no vmcnt drain), counted vmcnt(4) once per K-tile, half-tile staged
//     prefetch 1-2 tiles ahead (dead-half overwrite proof in comments),
//     fragment-permuted LDS (conflict-free ds_read_b128), setprio around MFMA.

typedef unsigned short u16;
typedef unsigned int u32;
typedef __bf16 bf16x8 __attribute__((ext_vector_type(8)));
typedef float f32x4 __attribute__((ext_vector_type(4)));

#define RAW_BAR() asm volatile("s_barrier" ::: "memory")
#define WAITV(N) asm volatile("s_waitcnt vmcnt(" #N ")" ::: "memory")

__device__ __forceinline__ float bf2f(u16 u) {
    union { unsigned int i; float f; } c; c.i = ((unsigned int)u) << 16; return c.f;
}
__device__ __forceinline__ u16 f2bf(float f) {
    union { float f; unsigned int i; } c; c.f = f;
    unsigned int b = c.i;
    return (u16)((b + 0x7fffu + ((b >> 16) & 1u)) >> 16);
}
__device__ __forceinline__ float gelu_f(float x) {
    float y = 0.7978845608028654f * (x + 0.044715f * x * x * x);
    float t = __expf(2.0f * y);
    float th = 1.0f - 2.0f / (t + 1.0f);  // tanh(y)
    return 0.5f * x * (1.0f + th);
}
// Async global->LDS 16B per lane. LDS dest is wave-uniform base + lane*16.
__device__ __forceinline__ void async_cp16(const u16* g, u16* l) {
    __builtin_amdgcn_global_load_lds(
        (const __attribute__((address_space(1))) u32*)g,
        (__attribute__((address_space(3))) u32*)l, 16, 0, 0);
}

// ---------------------------------------------------------------------------
// 256x256 8-phase GEMM: C[M][N] = A[M][K] @ Bt[N][K]^T (+epilogue).
// 512 threads = 8 waves (2M x 4N), per-wave 128x64 output, BK=64.
// LDS 128 KiB: A/B x 2 halves(128 rows) x double-buffer, fragment-permuted:
// (row,k) -> vec8 slot ((row/16)*2 + (k/32))*64 + ((k%32)/8)*16 + (row%16)
// so every ds_read_b128 is a contiguous 1024B wave read (conflict-free).
// Schedule per K-tile T (4 phases):
//   ph: {ds_read A-subtile (+ all B at ph0, reg-resident for the K-tile);
//        stage one half-tile; s_barrier; lgkmcnt0; setprio1; 16 MFMA;
//        setprio0; [ph3: vmcnt(4)]; s_barrier}
// Staging: ph0/1 -> A(T+1) halves (opposite buffer, always safe);
//          ph2/3 -> B(T+2) halves over T's B (dead after T.ph0: B-frags
//          are read to regs at ph0, complete before ph0's MFMAs/barrier).
// Boundary vmcnt(4): exactly tile T+1 committed, B(T+2) (4 loads) in flight.
// EPI: 0 = fp32 partial (split-K, +s*cStep), 1 = bias+bf16, 3 = bias+gelu.
// ---------------------------------------------------------------------------
template<int EPI>
__global__ __launch_bounds__(512, 2) void gemm256_k(
    const u16* __restrict__ A, int lda, int aStep,
    const u16* __restrict__ Bt, int ldb, int bStep,
    void* __restrict__ Cv, int ldc, long long cStep,
    const float* __restrict__ bias, int K)
{
    __shared__ __align__(16) u16 As[2][2][128 * 64];
    __shared__ __align__(16) u16 Bs[2][2][128 * 64];
    const int t = threadIdx.x;
    const int lane = t & 63;
    const int w = t >> 6;
    const int wr = w >> 2, wc = w & 3;       // 2M x 4N wave grid
    const int s = blockIdx.z;                // split-K index
    const u16* Ab = A + (size_t)blockIdx.x * 256 * lda + (size_t)s * aStep;
    const u16* Bb = Bt + (size_t)blockIdx.y * 256 * ldb + (size_t)s * bStep;
    const int nkt = K >> 6;

    auto stage_half = [&](u16* dst, const u16* src, int ld, int k0) {
#pragma unroll
        for (int p = 0; p < 2; ++p) {
            int idx8 = p * 512 + t;
            int grp = idx8 >> 6, l6 = idx8 & 63;
            int row = (grp >> 1) * 16 + (l6 & 15);
            int k = (grp & 1) * 32 + (l6 >> 4) * 8;
            int base8 = p * 512 + (t & ~63);  // wave-uniform LDS base
            async_cp16(src + (size_t)row * ld + k0 + k, dst + base8 * 8);
        }
    };

    // Prologue: tile0 complete + tile1 B-halves. vmcnt(4) = tile0 committed.
    stage_half(As[0][0], Ab, lda, 0);
    stage_half(As[0][1], Ab + (size_t)128 * lda, lda, 0);
    stage_half(Bs[0][0], Bb, ldb, 0);
    stage_half(Bs[0][1], Bb + (size_t)128 * ldb, ldb, 0);
    if (1 < nkt) {
        stage_half(Bs[1][0], Bb, ldb, 64);
        stage_half(Bs[1][1], Bb + (size_t)128 * ldb, ldb, 64);
        WAITV(4);
    } else {
        WAITV(0);
    }
    RAW_BAR();

    f32x4 acc[8][4];
#pragma unroll
    for (int m = 0; m < 8; ++m)
#pragma unroll
        for (int n = 0; n < 4; ++n)
            acc[m][n] = (f32x4){0.f, 0.f, 0.f, 0.f};

    for (int T = 0; T < nkt; ++T) {
        const int buf = T & 1;
        const u16* Ah = As[buf][wr];         // this wave's A half (128 rows)
        const u16* Bh = Bs[buf][wc >> 1];    // this wave's B half
        bf16x8 bF[4][2];
#pragma unroll
        for (int ph = 0; ph < 4; ++ph) {
            bf16x8 aP[2][2];
#pragma unroll
            for (int mi = 0; mi < 2; ++mi)
#pragma unroll
                for (int ks = 0; ks < 2; ++ks)
                    aP[mi][ks] = *(const bf16x8*)(
                        &Ah[(((2 * ph + mi) * 2 + ks) * 64 + lane) * 8]);
            if (ph == 0) {
#pragma unroll
                for (int n = 0; n < 4; ++n)
#pragma unroll
                    for (int ks = 0; ks < 2; ++ks)
                        bF[n][ks] = *(const bf16x8*)(
                            &Bh[((((wc & 1) * 4 + n) * 2 + ks) * 64 + lane) * 8]);
            }
            // Prefetch one half-tile per phase.
            if (ph < 2) {
                if (T + 1 < nkt)
                    stage_half(As[(T + 1) & 1][ph],
                               Ab + (size_t)(ph * 128) * lda, lda, (T + 1) * 64);
            } else {
                if (T + 2 < nkt)
                    stage_half(Bs[buf][ph - 2],
                               Bb + (size_t)((ph - 2) * 128) * ldb, ldb,
                               (T + 2) * 64);
            }
            RAW_BAR();
            asm volatile("s_waitcnt lgkmcnt(0)" ::: "memory");
            __builtin_amdgcn_s_setprio(1);
#pragma unroll
            for (int mi = 0; mi < 2; ++mi)
#pragma unroll
                for (int n = 0; n < 4; ++n)
#pragma unroll
                    for (int ks = 0; ks < 2; ++ks)
                        acc[2 * ph + mi][n] = __builtin_amdgcn_mfma_f32_16x16x32_bf16(
                            aP[mi][ks], bF[n][ks], acc[2 * ph + mi][n], 0, 0, 0);
            __builtin_amdgcn_s_setprio(0);
            if (ph == 3) {
                if (T + 3 <= nkt) { WAITV(4); }       // steady: B(T+2) in flight
                else if (T + 2 == nkt) { WAITV(0); }  // drain before last tile
            }
            RAW_BAR();
        }
    }

    // C/D layout: col = lane&15, row = (lane>>4)*4 + reg.
    const int q4 = lane >> 4, cn = lane & 15;
#pragma unroll
    for (int m = 0; m < 8; ++m) {
#pragma unroll
        for (int n = 0; n < 4; ++n) {
            int mBase = blockIdx.x * 256 + wr * 128 + m * 16 + q4 * 4;
            int n0 = blockIdx.y * 256 + wc * 64 + n * 16 + cn;
#pragma unroll
            for (int r = 0; r < 4; ++r) {
                int mm = mBase + r;
                float v = acc[m][n][r];
                if constexpr (EPI == 0) {
                    float* Cp = (float*)Cv + (size_t)s * cStep;
                    Cp[(size_t)mm * ldc + n0] = v;
                } else if constexpr (EPI == 1) {
                    v += bias[n0];
                    ((u16*)Cv)[(size_t)mm * ldc + n0] = f2bf(v);
                } else {  // EPI == 3
                    v += bias[n0];
                    v = gelu_f(v);
                    ((u16*)Cv)[(size_t)mm * ldc + n0] = f2bf(v);
                }
            }
        }
    }
}

// Weight transpose+convert: src fp32 [K][N] -> dst bf16 [N][K], batch z.
__global__ __launch_bounds__(256) void transpose_w_k(
    const float* __restrict__ src, u16* __restrict__ dst, int K, int N)
{
    __shared__ float tile[32][33];
    const int n0 = blockIdx.x * 32, k0 = blockIdx.y * 32;
    const size_t zoff = (size_t)blockIdx.z * K * N;
    src += zoff;
    dst += zoff;
    const int tx = threadIdx.x & 31, ty = threadIdx.x >> 5;
#pragma unroll
    for (int i = 0; i < 4; ++i) {
        int k = k0 + ty + i * 8;
        tile[ty + i * 8][tx] = src[(size_t)k * N + n0 + tx];
    }
    __syncthreads();
#pragma unroll
    for (int i = 0; i < 4; ++i) {
        int n = n0 + ty + i * 8;
        dst[(size_t)n * K + k0 + tx] = f2bf(tile[tx][ty + i * 8]);
    }
}

// V transpose: Vt[z][d][j] = qkv[b*512+j][1536 + h*64 + d], bf16.
__global__ __launch_bounds__(256) void vtrans_k(
    const u16* __restrict__ qkv, u16* __restrict__ vt)
{
    __shared__ u16 tile[32][66];
    const int z = blockIdx.y;
    const int b = z / 12, h = z % 12;
    const int jc = blockIdx.x * 32;
    const int d = threadIdx.x & 63, jj = threadIdx.x >> 6;
    const u16* src = qkv + (size_t)b * 512 * 2304 + 1536 + (size_t)h * 64;
#pragma unroll
    for (int i = 0; i < 8; ++i) {
        int j = jc + jj + i * 4;
        tile[jj + i * 4][d] = src[(size_t)j * 2304 + d];
    }
    __syncthreads();
    const int jx = threadIdx.x & 31, dd0 = threadIdx.x >> 5;
    u16* dstz = vt + (size_t)z * 64 * 512;
#pragma unroll
    for (int i = 0; i < 8; ++i) {
        int dd = dd0 + i * 8;
        dstz[(size_t)dd * 512 + jc + jx] = tile[jx][dd];
    }
}

// ---------------------------------------------------------------------------
// Fused attention: per block = 32 q-rows of one (b,h). S=512, dh=64.
// ---------------------------------------------------------------------------
__global__ __launch_bounds__(256) void fattn_k(
    const u16* __restrict__ qkv, const u16* __restrict__ vt,
    u16* __restrict__ out, const int* __restrict__ amask)
{
    __shared__ __align__(16) u16 Qs[32 * 64];        // 4KB, frag layout
    __shared__ __align__(16) u16 KVs[2][64 * 64];    // 16KB dbuf, frag layout
    __shared__ __align__(16) u16 Ps[32 * 512];       // 32KB, swizzled row-major
    __shared__ float red[4][32];

    const int t = threadIdx.x;
    const int lane = t & 63;
    const int w = t >> 6;              // wave id: col tile (phase A) / d tile (B)
    const int q4 = lane >> 4, cn = lane & 15;
    const int z = blockIdx.x;          // 96 = b*12+h
    const int b = z / 12, h = z % 12;
    const int x = 15 - (int)blockIdx.y;  // heavy (large-nch) tiles dispatch first
    const int q0 = x * 32;
    const int nch = (q0 + 32 + 63) >> 6;  // causal: chunks of 64 cols, 1..8

    const u16* Qg = qkv + (size_t)(b * 512 + q0) * 2304 + h * 64;
    const u16* Kg = qkv + (size_t)(b * 512) * 2304 + 768 + h * 64;
    const u16* Vg = vt + (size_t)z * 64 * 512;

    // ---- stage Q (32x64 -> frag layout, one 16B op/thread) + K chunk 0 ----
    {
        int grp = t >> 6, l6 = t & 63;
        int row = (grp >> 1) * 16 + (l6 & 15);
        int k = (grp & 1) * 32 + (l6 >> 4) * 8;
        int base8 = t & ~63;
        async_cp16(Qg + (size_t)row * 2304 + k, &Qs[base8 * 8]);
    }
    auto stageK = [&](int c, int buf) {
#pragma unroll
        for (int p = 0; p < 2; ++p) {
            int idx8 = p * 256 + t;
            int grp = idx8 >> 6, l6 = idx8 & 63;
            int row = (grp >> 1) * 16 + (l6 & 15);   // j within chunk
            int k = (grp & 1) * 32 + (l6 >> 4) * 8;  // d
            int base8 = p * 256 + (t & ~63);
            async_cp16(Kg + (size_t)(c * 64 + row) * 2304 + k,
                       &KVs[buf][base8 * 8]);
        }
    };
    auto stageV = [&](int c, int buf) {
#pragma unroll
        for (int p = 0; p < 2; ++p) {
            int idx8 = p * 256 + t;
            int grp = idx8 >> 6, l6 = idx8 & 63;
            int row = (grp >> 1) * 16 + (l6 & 15);   // d
            int k = (grp & 1) * 32 + (l6 >> 4) * 8;  // j within chunk
            int base8 = p * 256 + (t & ~63);
            async_cp16(Vg + (size_t)row * 512 + c * 64 + k,
                       &KVs[buf][base8 * 8]);
        }
    };
    stageK(0, 0);
    __syncthreads();

    bf16x8 qF[2][2];
#pragma unroll
    for (int i = 0; i < 2; ++i)
#pragma unroll
        for (int ks = 0; ks < 2; ++ks)
            qF[i][ks] = *(const bf16x8*)(&Qs[((i * 2 + ks) * 64 + lane) * 8]);

    f32x4 acc[2][8];
#pragma unroll
    for (int i = 0; i < 2; ++i)
#pragma unroll
        for (int c = 0; c < 8; ++c)
            acc[i][c] = (f32x4){0.f, 0.f, 0.f, 0.f};

    // ---- Phase A: S chunks. wave w computes cols w*16+cn of each chunk ----
#pragma unroll
    for (int c = 0; c < 8; ++c) {
        if (c < nch) {  // block-uniform
            if (c + 1 < nch) stageK(c + 1, (c + 1) & 1);
            else stageV(0, nch & 1);  // prefetch first V chunk
            const u16* Kb = KVs[c & 1];
#pragma unroll
            for (int ks = 0; ks < 2; ++ks) {
                bf16x8 bF = *(const bf16x8*)(&Kb[((w * 2 + ks) * 64 + lane) * 8]);
#pragma unroll
                for (int i = 0; i < 2; ++i)
                    acc[i][c] = __builtin_amdgcn_mfma_f32_16x16x32_bf16(
                        qF[i][ks], bF, acc[i][c], 0, 0, 0);
            }
            __syncthreads();
        }
    }

    // ---- mask + scale; running max ----
    float mx[2][4];
#pragma unroll
    for (int i = 0; i < 2; ++i)
#pragma unroll
        for (int r = 0; r < 4; ++r) mx[i][r] = -1e30f;
#pragma unroll
    for (int c = 0; c < 8; ++c) {
        if (c < nch) {
            int j = c * 64 + w * 16 + cn;
            float am = (1.0f - (float)amask[b * 512 + j]) * -10000.0f;
#pragma unroll
            for (int i = 0; i < 2; ++i)
#pragma unroll
                for (int r = 0; r < 4; ++r) {
                    int q = q0 + i * 16 + q4 * 4 + r;
                    float s = (j <= q) ? (acc[i][c][r] * 0.125f + am)
                                       : (-10000.0f + am);
                    acc[i][c][r] = s;
                    mx[i][r] = fmaxf(mx[i][r], s);
                }
        }
    }
#pragma unroll
    for (int i = 0; i < 2; ++i)
#pragma unroll
        for (int r = 0; r < 4; ++r) {
            float m = mx[i][r];
            m = fmaxf(m, __shfl_xor(m, 1));
            m = fmaxf(m, __shfl_xor(m, 2));
            m = fmaxf(m, __shfl_xor(m, 4));
            m = fmaxf(m, __shfl_xor(m, 8));
            mx[i][r] = m;
        }
    if (cn == 0) {
#pragma unroll
        for (int i = 0; i < 2; ++i)
#pragma unroll
            for (int r = 0; r < 4; ++r)
                red[w][i * 16 + q4 * 4 + r] = mx[i][r];
    }
    __syncthreads();
#pragma unroll
    for (int i = 0; i < 2; ++i)
#pragma unroll
        for (int r = 0; r < 4; ++r) {
            int q = i * 16 + q4 * 4 + r;
            mx[i][r] = fmaxf(fmaxf(red[0][q], red[1][q]),
                             fmaxf(red[2][q], red[3][q]));
        }
    __syncthreads();  // before red reuse for sums

    // ---- exp, write P (unnormalized bf16, swizzled), row sums ----
    float sm[2][4];
#pragma unroll
    for (int i = 0; i < 2; ++i)
#pragma unroll
        for (int r = 0; r < 4; ++r) sm[i][r] = 0.f;
#pragma unroll
    for (int c = 0; c < 8; ++c) {
        if (c < nch) {
            int j = c * 64 + w * 16 + cn;
#pragma unroll
            for (int i = 0; i < 2; ++i)
#pragma unroll
                for (int r = 0; r < 4; ++r) {
                    float p = __expf(acc[i][c][r] - mx[i][r]);
                    sm[i][r] += p;
                    int row = i * 16 + q4 * 4 + r;
                    int sw = (row & 7) ^ ((row >> 3) & 1);
                    Ps[row * 512 + (j ^ (sw << 3))] = f2bf(p);
                }
        }
    }
#pragma unroll
    for (int i = 0; i < 2; ++i)
#pragma unroll
        for (int r = 0; r < 4; ++r) {
            float s = sm[i][r];
            s += __shfl_xor(s, 1);
            s += __shfl_xor(s, 2);
            s += __shfl_xor(s, 4);
            s += __shfl_xor(s, 8);
            sm[i][r] = s;
        }
    if (cn == 0) {
#pragma unroll
        for (int i = 0; i < 2; ++i)
#pragma unroll
            for (int r = 0; r < 4; ++r)
                red[w][i * 16 + q4 * 4 + r] = sm[i][r];
    }
    __syncthreads();
    float inv[2][4];
#pragma unroll
    for (int i = 0; i < 2; ++i)
#pragma unroll
        for (int r = 0; r < 4; ++r) {
            int q = i * 16 + q4 * 4 + r;
            inv[i][r] = 1.0f / (red[0][q] + red[1][q] + red[2][q] + red[3][q]);
        }

    // ---- Phase B: attn = P @ V. wave w computes d cols w*16+cn ----
    f32x4 acc2[2];
    acc2[0] = (f32x4){0.f, 0.f, 0.f, 0.f};
    acc2[1] = (f32x4){0.f, 0.f, 0.f, 0.f};
#pragma unroll
    for (int c = 0; c < 8; ++c) {
        if (c < nch) {
            if (c + 1 < nch) stageV(c + 1, (nch + c + 1) & 1);
            const u16* Vb = KVs[(nch + c) & 1];
#pragma unroll
            for (int ks = 0; ks < 2; ++ks) {
                bf16x8 vF = *(const bf16x8*)(&Vb[((w * 2 + ks) * 64 + lane) * 8]);
                int jb = c * 64 + ks * 32 + q4 * 8;
#pragma unroll
                for (int i = 0; i < 2; ++i) {
                    int prow = i * 16 + cn;
                    int sw = (prow & 7) ^ ((prow >> 3) & 1);
                    bf16x8 pF = *(const bf16x8*)(
                        &Ps[prow * 512 + (jb ^ (sw << 3))]);
                    acc2[i] = __builtin_amdgcn_mfma_f32_16x16x32_bf16(
                        pF, vF, acc2[i], 0, 0, 0);
                }
            }
            __syncthreads();
        }
    }

    // ---- epilogue: scale by 1/sum, write bf16 [4096][768] ----
#pragma unroll
    for (int i = 0; i < 2; ++i)
#pragma unroll
        for (int r = 0; r < 4; ++r) {
            int q = q0 + i * 16 + q4 * 4 + r;
            out[(size_t)(b * 512 + q) * 768 + h * 64 + w * 16 + cn] =
                f2bf(acc2[i][r] * inv[i][r]);
        }
}

// Fused split-K reduce + bias + residual + LayerNorm. One block per row.
// x = sum_p parts[p] + bias + res ; out = LN(x)*g + b (fp32 + bf16 copies).
template<int NP>
__global__ __launch_bounds__(256) void reduce_ln_k(
    const float* __restrict__ parts, const float* __restrict__ bias,
    const float* __restrict__ res, const float* __restrict__ g,
    const float* __restrict__ b, float* __restrict__ out, u16* __restrict__ outb)
{
    __shared__ float red[4];
    const int r = blockIdx.x, t = threadIdx.x;
    const size_t base = (size_t)r * 768;
    float v[3];
#pragma unroll
    for (int i = 0; i < 3; ++i) {
        const int d = t + i * 256;
        float x = res[base + d] + bias[d];
#pragma unroll
        for (int p = 0; p < NP; ++p)
            x += parts[(size_t)p * 4096 * 768 + base + d];
        v[i] = x;
    }
    float s = v[0] + v[1] + v[2];
    for (int o = 1; o < 64; o <<= 1) s += __shfl_xor(s, o);
    if ((t & 63) == 0) red[t >> 6] = s;
    __syncthreads();
    const float mean = (red[0] + red[1] + red[2] + red[3]) * (1.0f / 768.0f);
    __syncthreads();
    float d0 = v[0] - mean, d1 = v[1] - mean, d2 = v[2] - mean;
    float s2 = d0 * d0 + d1 * d1 + d2 * d2;
    for (int o = 1; o < 64; o <<= 1) s2 += __shfl_xor(s2, o);
    if ((t & 63) == 0) red[t >> 6] = s2;
    __syncthreads();
    const float var = (red[0] + red[1] + red[2] + red[3]) * (1.0f / 768.0f);
    const float rs = rsqrtf(var + 1e-5f);
    float y0 = d0 * rs * g[t] + b[t];
    float y1 = d1 * rs * g[t + 256] + b[t + 256];
    float y2 = d2 * rs * g[t + 512] + b[t + 512];
    out[base + t] = y0; out[base + t + 256] = y1; out[base + t + 512] = y2;
    outb[base + t] = f2bf(y0);
    outb[base + t + 256] = f2bf(y1);
    outb[base + t + 512] = f2bf(y2);
}

// Embedding: h[r][d] = tok[ids[r]][d] + pos[r%512][d]; also bf16 copy.
__global__ __launch_bounds__(256) void embed_k(
    const int* __restrict__ ids, const float* __restrict__ tok,
    const float* __restrict__ pos, float* __restrict__ h, u16* __restrict__ hb)
{
    const int e = blockIdx.x * 256 + threadIdx.x;
    const int r = e / 768, d = e - r * 768;
    const int srow = r & 511;
    const int id = ids[r];
    const float v = tok[(size_t)id * 768 + d] + pos[(size_t)srow * 768 + d];
    h[e] = v;
    hb[e] = f2bf(v);
}

extern "C" void kernel_launch(void* const* d_in, const int* in_sizes, int n_in,
                              void* d_out, int out_size, void* d_ws, size_t ws_size,
                              hipStream_t stream)
{
    (void)in_sizes; (void)n_in; (void)out_size; (void)ws_size;
    const int*   ids  = (const int*)d_in[0];
    const int*   mask = (const int*)d_in[1];
    const float* tok  = (const float*)d_in[2];
    const float* pos  = (const float*)d_in[3];
    const float* Wqkv = (const float*)d_in[4];
    const float* bqkv = (const float*)d_in[5];
    const float* Wo   = (const float*)d_in[6];
    const float* bo   = (const float*)d_in[7];
    const float* g1   = (const float*)d_in[8];
    const float* b1   = (const float*)d_in[9];
    const float* Wfc  = (const float*)d_in[10];
    const float* bfc  = (const float*)d_in[11];
    const float* Wp2  = (const float*)d_in[12];
    const float* bp2  = (const float*)d_in[13];
    const float* g2   = (const float*)d_in[14];
    const float* b2   = (const float*)d_in[15];

    char* ws = (char*)d_ws;
    size_t off = 0;
    auto alloc = [&](size_t elems, size_t esz) {
        void* p = ws + off;
        off += (elems * esz + 255) & ~(size_t)255;
        return p;
    };
    u16*   WqkvT  = (u16*)alloc(12ull * 2304 * 768, 2);
    u16*   WoT    = (u16*)alloc(12ull * 768 * 768, 2);
    u16*   WfcT   = (u16*)alloc(12ull * 3072 * 768, 2);
    u16*   Wp2T   = (u16*)alloc(12ull * 768 * 3072, 2);
    float* h      = (float*)alloc(4096ull * 768, 4);
    u16*   hb     = (u16*)alloc(4096ull * 768, 2);
    u16*   qkvb   = (u16*)alloc(4096ull * 2304, 2);
    u16*   scores = (u16*)alloc(96ull * 512 * 512, 2);   // P2 partials (alias)
    u16*   Vt     = (u16*)alloc(96ull * 64 * 512, 2);
    u16*   attnb  = (u16*)alloc(4096ull * 768, 2);
    float* nbuf   = (float*)alloc(4096ull * 768, 4);
    u16*   nb     = (u16*)alloc(4096ull * 768, 2);
    u16*   fcb    = (u16*)alloc(4096ull * 3072, 2);      // aliased as P1 (2x fp32)
    float* P1 = (float*)fcb;     // 2*4096*768*4 B == 4096*3072*2 B
    float* P2 = (float*)scores;  // 4*4096*768*4 B == 96*512*512*2 B

    transpose_w_k<<<dim3(72, 24, 12), 256, 0, stream>>>(Wqkv, WqkvT, 768, 2304);
    transpose_w_k<<<dim3(24, 24, 12), 256, 0, stream>>>(Wo, WoT, 768, 768);
    transpose_w_k<<<dim3(96, 24, 12), 256, 0, stream>>>(Wfc, WfcT, 768, 3072);
    transpose_w_k<<<dim3(24, 96, 12), 256, 0, stream>>>(Wp2, Wp2T, 3072, 768);
    embed_k<<<12288, 256, 0, stream>>>(ids, tok, pos, h, hb);

    for (int l = 0; l < 12; ++l) {
        // qkv = h @ Wqkv + bqkv -> bf16 [4096][2304]
        gemm256_k<1><<<dim3(16, 9, 1), 512, 0, stream>>>(
            hb, 768, 0, WqkvT + (size_t)l * 2304 * 768, 768, 0,
            qkvb, 2304, 0, bqkv + l * 2304, 768);
        // Vt[z][d][j] for PV B-operand
        vtrans_k<<<dim3(16, 96), 256, 0, stream>>>(qkvb, Vt);
        // fused attention: QK^T + mask + softmax + PV -> attnb [4096][768]
        fattn_k<<<dim3(96, 16), 256, 0, stream>>>(qkvb, Vt, attnb, mask);
        // Wo, split-K=2 -> P1 partials (z = split)
        gemm256_k<0><<<dim3(16, 3, 2), 512, 0, stream>>>(
            attnb, 768, 384, WoT + (size_t)l * 768 * 768, 768, 384,
            P1, 768, 4096LL * 768, nullptr, 384);
        // n = LN(h + attn@Wo + bo) -> nbuf fp32 + nb bf16
        reduce_ln_k<2><<<4096, 256, 0, stream>>>(
            P1, bo + l * 768, h, g1 + l * 768, b1 + l * 768, nbuf, nb);
        // fc = gelu(n @ Wfc + bfc) -> bf16 [4096][3072]  (overwrites P1)
        gemm256_k<3><<<dim3(16, 12, 1), 512, 0, stream>>>(
            nb, 768, 0, WfcT + (size_t)l * 3072 * 768, 768, 0,
            fcb, 3072, 0, bfc + l * 3072, 768);
        // Wp2, split-K=4 -> P2 partials (overwrites scores region)
        gemm256_k<0><<<dim3(16, 3, 4), 512, 0, stream>>>(
            fcb, 3072, 768, Wp2T + (size_t)l * 768 * 3072, 3072, 768,
            P2, 768, 4096LL * 768, nullptr, 768);
        // h' = LN(n + fc@Wp2 + bp2) -> h/d_out fp32 + hb bf16
        float* dsth = (l == 11) ? (float*)d_out : h;
        reduce_ln_k<4><<<4096, 256, 0, stream>>>(
            P2, bp2 + l * 768, nbuf, g2 + l * 768, b2 + l * 768, dsth, hb);
    }
}